// Round 7
// baseline (288.028 us; speedup 1.0000x reference)
//
#include <hip/hip_runtime.h>

#define NB 4
#define NS 2048
#define NE 1024
#define NH 16
#define ND 64
#define KVB 64

typedef unsigned short ushort_t;
typedef __attribute__((ext_vector_type(8))) short bf16x8;
typedef __attribute__((ext_vector_type(4))) float f32x4;

static __device__ __forceinline__ ushort_t f2bf(float f) {
    union { float f; unsigned int u; } v; v.f = f;
    unsigned int r = v.u + 0x7FFF + ((v.u >> 16) & 1);   // RNE
    return (ushort_t)(r >> 16);
}

static __device__ __forceinline__ unsigned pk_bf16(float lo, float hi) {
    unsigned r;
    asm("v_cvt_pk_bf16_f32 %0, %1, %2" : "=v"(r) : "v"(lo), "v"(hi));
    return r;
}

static __device__ __forceinline__ void gload16(const void* g, void* l) {
    __builtin_amdgcn_global_load_lds(
        (const __attribute__((address_space(1))) void*)g,
        (__attribute__((address_space(3))) void*)l,
        16, 0, 0);
}

// ===========================================================================
// fp32 -> bf16 bulk convert  (verified)
// ===========================================================================
__global__ __launch_bounds__(256)
void cvt_f32_bf16(const float* __restrict__ src, ushort_t* __restrict__ dst, int n8)
{
    const int i = blockIdx.x * 256 + threadIdx.x;
    if (i >= n8) return;
    const float4 a = ((const float4*)src)[i * 2];
    const float4 b = ((const float4*)src)[i * 2 + 1];
    union { ushort_t us[8]; uint4 v; } pk;
    pk.us[0] = f2bf(a.x); pk.us[1] = f2bf(a.y); pk.us[2] = f2bf(a.z); pk.us[3] = f2bf(a.w);
    pk.us[4] = f2bf(b.x); pk.us[5] = f2bf(b.y); pk.us[6] = f2bf(b.z); pk.us[7] = f2bf(b.w);
    ((uint4*)dst)[i] = pk.v;
}

// ===========================================================================
// bf16 MFMA GEMM (m97 structure) — verified rounds 2-5, r5 version verbatim
// ===========================================================================
template<int EPI>
__global__ __launch_bounds__(256)
void gemm_bf16(const ushort_t* __restrict__ A, const ushort_t* __restrict__ W,
               const float* __restrict__ bias, float* __restrict__ C,
               ushort_t* __restrict__ Cb, int M, int N, int K)
{
    __shared__ ushort_t As[128 * 32];
    __shared__ ushort_t Bs[128 * 32];
    const int tid  = threadIdx.x;
    const int lane = tid & 63;
    const int wid  = tid >> 6;
    const int lr   = lane & 15;
    const int lg   = lane >> 4;
    const int m0 = blockIdx.y * 128;
    const int n0 = blockIdx.x * 128;
    const int wr = wid >> 1, wc = wid & 1;

    size_t srcoff[2];
    int ldsoff[2];
#pragma unroll
    for (int p = 0; p < 2; ++p) {
        const int chunk = p * 256 + tid;
        const int row = chunk >> 2;
        const int sp  = chunk & 3;
        const int c   = sp ^ ((row >> 1) & 3);
        srcoff[p] = (size_t)row * K + c * 8;
        ldsoff[p] = (p * 256 + wid * 64) * 8;
    }
    const ushort_t* Ag = A + (size_t)m0 * K;
    const ushort_t* Wg = W + (size_t)n0 * K;

    int offa[4], offb[4];
#pragma unroll
    for (int f = 0; f < 4; ++f) {
        const int ra = wr * 64 + f * 16 + lr;
        offa[f] = ra * 32 + (lg ^ ((ra >> 1) & 3)) * 8;
        const int rb = wc * 64 + f * 16 + lr;
        offb[f] = rb * 32 + (lg ^ ((rb >> 1) & 3)) * 8;
    }

    f32x4 acc[4][4];
#pragma unroll
    for (int i = 0; i < 4; ++i)
#pragma unroll
        for (int j = 0; j < 4; ++j) acc[i][j] = (f32x4){0.f, 0.f, 0.f, 0.f};

    for (int k0 = 0; k0 < K; k0 += 32) {
        __syncthreads();
#pragma unroll
        for (int p = 0; p < 2; ++p) {
            gload16(Ag + srcoff[p] + k0, (ushort_t*)As + ldsoff[p]);
            gload16(Wg + srcoff[p] + k0, (ushort_t*)Bs + ldsoff[p]);
        }
        __syncthreads();
        bf16x8 af[4], bfr[4];
#pragma unroll
        for (int f = 0; f < 4; ++f) {
            af[f]  = *(const bf16x8*)&As[offa[f]];
            bfr[f] = *(const bf16x8*)&Bs[offb[f]];
        }
#pragma unroll
        for (int mf = 0; mf < 4; ++mf)
#pragma unroll
            for (int nf = 0; nf < 4; ++nf)
                acc[mf][nf] = __builtin_amdgcn_mfma_f32_16x16x32_bf16(
                    af[mf], bfr[nf], acc[mf][nf], 0, 0, 0);
    }

    if (EPI == 0) {
#pragma unroll
        for (int nf = 0; nf < 4; ++nf) {
            const int n = n0 + wc * 64 + nf * 16 + lr;
            const float bj = bias[n];
#pragma unroll
            for (int mf = 0; mf < 4; ++mf)
#pragma unroll
                for (int r = 0; r < 4; ++r) {
                    const int m = m0 + wr * 64 + mf * 16 + lg * 4 + r;
                    C[(size_t)m * N + n] = acc[mf][nf][r] + bj;
                }
        }
    } else {
#pragma unroll
        for (int nf = 0; nf < 4; ++nf) {
            const int n = n0 + wc * 64 + nf * 16 + lr;
            const float bj = bias[n];
            const int t = n >> 10;
            const int h = (n >> 6) & (NH - 1);
            const int d = n & (ND - 1);
#pragma unroll
            for (int mf = 0; mf < 4; ++mf)
#pragma unroll
                for (int r = 0; r < 4; ++r) {
                    const int m = m0 + wr * 64 + mf * 16 + lg * 4 + r;
                    const int b = m >> 11;
                    const int s = m & (NS - 1);
                    Cb[((size_t)((t * NB + b) * NH + h) * NS + s) * ND + d] =
                        f2bf(acc[mf][nf][r] + bj);
                }
        }
    }
}

// ===========================================================================
// RoPE in place on bf16 q,k — r5 version verbatim (verified)
// ===========================================================================
__global__ __launch_bounds__(256)
void rope_bf16(ushort_t* __restrict__ qkvb, const float* __restrict__ cosT,
               const float* __restrict__ sinT)
{
    const int idx = blockIdx.x * 256 + threadIdx.x;
    const int d0 = (idx & 3) * 8;
    const int s  = (idx >> 2) & (NS - 1);
    const int h  = (idx >> 13) & (NH - 1);
    const int b  = (idx >> 17) & (NB - 1);
    const int t  = idx >> 19;
    ushort_t* base = qkvb + ((size_t)((t * NB + b) * NH + h) * NS + s) * ND;

    union { ushort_t us[8]; uint4 v; } lo, hi, loo, hio;
    lo.v = *(const uint4*)(base + d0);
    hi.v = *(const uint4*)(base + d0 + 32);
    const float4 c0 = *(const float4*)(cosT + s * ND + d0);
    const float4 c1 = *(const float4*)(cosT + s * ND + d0 + 4);
    const float4 s0 = *(const float4*)(sinT + s * ND + d0);
    const float4 s1 = *(const float4*)(sinT + s * ND + d0 + 4);
    const float cc[8] = {c0.x, c0.y, c0.z, c0.w, c1.x, c1.y, c1.z, c1.w};
    const float ss[8] = {s0.x, s0.y, s0.z, s0.w, s1.x, s1.y, s1.z, s1.w};
#pragma unroll
    for (int j = 0; j < 8; ++j) {
        union { unsigned u; float f; } a, bb;
        a.u  = ((unsigned)lo.us[j]) << 16;
        bb.u = ((unsigned)hi.us[j]) << 16;
        loo.us[j] = f2bf(a.f * cc[j] - bb.f * ss[j]);
        hio.us[j] = f2bf(bb.f * cc[j] + a.f * ss[j]);
    }
    *(uint4*)(base + d0)      = loo.v;
    *(uint4*)(base + d0 + 32) = hio.v;
}

// ===========================================================================
// Swapped-operand bf16 MFMA flash attention — r5 base, ONLY change:
// 4 strips/wave (64 q-rows/wave, 256-q block), K/V fragments hoisted to
// registers and reused across the 4 strips. All LDS layouts, barriers,
// softmax math (exp(s*0.125)) identical to the verified r5 kernel.
// ===========================================================================
__global__ __launch_bounds__(256)
void attn_kernel(const ushort_t* __restrict__ qkvb, ushort_t* __restrict__ obuf)
{
    __shared__ ushort_t Ks[64 * 72];
    __shared__ ushort_t Vs[64 * 64];
    __shared__ ushort_t Ps[256 * 72];

    const int tid  = threadIdx.x;
    const int lane = tid & 63;
    const int wid  = tid >> 6;
    const int lr   = lane & 15;
    const int lg   = lane >> 4;
    const int bh = blockIdx.y;
    const int b = bh >> 4, h = bh & (NH - 1);
    const int q0 = blockIdx.x * 256;

    const ushort_t* qbase = qkvb + ((size_t)((0 * NB + b) * NH + h)) * (NS * ND);
    const ushort_t* kbase = qkvb + ((size_t)((1 * NB + b) * NH + h)) * (NS * ND);
    const ushort_t* vbase = qkvb + ((size_t)((2 * NB + b) * NH + h)) * (NS * ND);

    // Q fragments in registers (B operand): qf[strip][k-half]
    bf16x8 qf[4][2];
#pragma unroll
    for (int st = 0; st < 4; ++st)
#pragma unroll
        for (int kh = 0; kh < 2; ++kh)
            qf[st][kh] = *(const bf16x8*)(qbase + (size_t)(q0 + wid * 64 + st * 16 + lr) * ND
                                          + kh * 32 + lg * 8);

    // staging indices: thread covers rows {tid>>3, 32+(tid>>3)}, chunk tid&7
    const int sc = tid & 7;
    const int sr0 = tid >> 3;

    uint4 krg[2], vrg[2];
#pragma unroll
    for (int it = 0; it < 2; ++it) {
        const int r = sr0 + it * 32;
        krg[it] = *(const uint4*)(kbase + r * ND + sc * 8);
        vrg[it] = *(const uint4*)(vbase + r * ND + sc * 8);
    }

    f32x4 acc_o[4][4];
    float lsum[4] = {0.f, 0.f, 0.f, 0.f};
#pragma unroll
    for (int st = 0; st < 4; ++st)
#pragma unroll
        for (int dk = 0; dk < 4; ++dk) acc_o[st][dk] = (f32x4){0.f, 0.f, 0.f, 0.f};

    for (int kt = 0; kt < NS; kt += KVB) {
        __syncthreads();                         // B1: prev tile reads done
        // ---- stage K (row-major pad 72) and V (d-major, XOR swizzle) ----
#pragma unroll
        for (int it = 0; it < 2; ++it) {
            const int r = sr0 + it * 32;
            *(uint4*)&Ks[r * 72 + sc * 8] = krg[it];
            union { uint4 v; ushort_t us[8]; } pu;
            pu.v = vrg[it];
#pragma unroll
            for (int j = 0; j < 8; ++j) {
                const int sw = (j ^ sc) << 4;
                Vs[(sc * 8 + j) * 64 + ((((r * 2) ^ sw)) >> 1)] = pu.us[j];
            }
        }
        __syncthreads();                         // B2: staging visible
        // ---- T14: issue next tile's global loads (hide under compute) ----
        if (kt + KVB < NS) {
#pragma unroll
            for (int it = 0; it < 2; ++it) {
                const int r = kt + KVB + sr0 + it * 32;
                krg[it] = *(const uint4*)(kbase + (size_t)r * ND + sc * 8);
                vrg[it] = *(const uint4*)(vbase + (size_t)r * ND + sc * 8);
            }
        }

        // ---- K fragments once, reused by all 4 strips ----
        bf16x8 kf[2][4];
#pragma unroll
        for (int kh = 0; kh < 2; ++kh)
#pragma unroll
            for (int kvf = 0; kvf < 4; ++kvf)
                kf[kh][kvf] = *(const bf16x8*)&Ks[(kvf * 16 + lr) * 72 + kh * 32 + lg * 8];

        // ---- per strip: S^T = K Q^T, softmax, packed P store ----
#pragma unroll
        for (int st = 0; st < 4; ++st) {
            f32x4 s[4];
#pragma unroll
            for (int kvf = 0; kvf < 4; ++kvf) s[kvf] = (f32x4){0.f, 0.f, 0.f, 0.f};
#pragma unroll
            for (int kh = 0; kh < 2; ++kh)
#pragma unroll
                for (int kvf = 0; kvf < 4; ++kvf)
                    s[kvf] = __builtin_amdgcn_mfma_f32_16x16x32_bf16(
                        kf[kh][kvf], qf[st][kh], s[kvf], 0, 0, 0);

            const int prow = (wid * 64 + st * 16 + lr) * 72;
#pragma unroll
            for (int kvf = 0; kvf < 4; ++kvf) {
                const float p0 = __expf(s[kvf][0] * 0.125f);
                const float p1 = __expf(s[kvf][1] * 0.125f);
                const float p2 = __expf(s[kvf][2] * 0.125f);
                const float p3 = __expf(s[kvf][3] * 0.125f);
                lsum[st] += (p0 + p1) + (p2 + p3);
                const unsigned w01 = pk_bf16(p0, p1);
                const unsigned w23 = pk_bf16(p2, p3);
                *(uint2*)&Ps[prow + kvf * 16 + lg * 4] = make_uint2(w01, w23);
            }
        }
        __syncthreads();                         // B3: P visible

        // ---- O += P V  (V fragments held per kh, reused by 4 strips) ----
#pragma unroll
        for (int kh = 0; kh < 2; ++kh) {
            bf16x8 vf[4];
#pragma unroll
            for (int dk = 0; dk < 4; ++dk) {
                const int d = dk * 16 + lr;
                const int sw = ((d & 7) ^ ((d >> 3) & 7)) << 4;
                vf[dk] = *(const bf16x8*)&Vs[d * 64 + (((kh * 64 + lg * 16) ^ sw) >> 1)];
            }
#pragma unroll
            for (int st = 0; st < 4; ++st) {
                const bf16x8 pf = *(const bf16x8*)&Ps[(wid * 64 + st * 16 + lr) * 72
                                                      + kh * 32 + lg * 8];
#pragma unroll
                for (int dk = 0; dk < 4; ++dk)
                    acc_o[st][dk] = __builtin_amdgcn_mfma_f32_16x16x32_bf16(
                        pf, vf[dk], acc_o[st][dk], 0, 0, 0);
            }
        }
    }

    // ---- epilogue: row-sum reduce, redistribute, write bf16 O ----
#pragma unroll
    for (int st = 0; st < 4; ++st) {
        float r = lsum[st];
        r += __shfl_xor(r, 16);
        r += __shfl_xor(r, 32);
        float invq[4];
#pragma unroll
        for (int reg = 0; reg < 4; ++reg)
            invq[reg] = 1.0f / __shfl(r, lg * 4 + reg);
#pragma unroll
        for (int dk = 0; dk < 4; ++dk)
#pragma unroll
            for (int reg = 0; reg < 4; ++reg) {
                const int q = q0 + wid * 64 + st * 16 + lg * 4 + reg;
                const int d = dk * 16 + lr;
                obuf[((size_t)(b * NS + q)) * NE + h * ND + d] =
                    f2bf(acc_o[st][dk][reg] * invq[reg]);
            }
    }
}

// ===========================================================================
extern "C" void kernel_launch(void* const* d_in, const int* in_sizes, int n_in,
                              void* d_out, int out_size, void* d_ws, size_t ws_size,
                              hipStream_t stream)
{
    const float* x    = (const float*)d_in[0];
    const float* Win  = (const float*)d_in[1];
    const float* bin  = (const float*)d_in[2];
    const float* Wout = (const float*)d_in[3];
    const float* bout = (const float*)d_in[4];
    const float* cosT = (const float*)d_in[5];
    const float* sinT = (const float*)d_in[6];
    float* out  = (float*)d_out;

    ushort_t* qkvb  = (ushort_t*)d_ws;
    ushort_t* obufb = qkvb + (size_t)3 * NB * NH * NS * ND;
    ushort_t* xb    = obufb + (size_t)NB * NS * NE;
    ushort_t* Wib   = xb + (size_t)NB * NS * NE;
    ushort_t* Wob   = Wib + (size_t)3 * NE * NE;

    const int nx = NB * NS * NE;
    const int nwi = 3 * NE * NE;
    const int nwo = NE * NE;

    cvt_f32_bf16<<<nx / 2048, 256, 0, stream>>>(x, xb, nx / 8);
    cvt_f32_bf16<<<nwi / 2048, 256, 0, stream>>>(Win, Wib, nwi / 8);
    cvt_f32_bf16<<<nwo / 2048, 256, 0, stream>>>(Wout, Wob, nwo / 8);

    gemm_bf16<1><<<dim3(3 * NE / 128, NB * NS / 128), 256, 0, stream>>>(
        xb, Wib, bin, nullptr, qkvb, NB * NS, 3 * NE, NE);
    rope_bf16<<<(2 * NB * NH * NS * 4) / 256, 256, 0, stream>>>(qkvb, cosT, sinT);
    attn_kernel<<<dim3(NS / 256, NB * NH), 256, 0, stream>>>(qkvb, obufb);
    gemm_bf16<0><<<dim3(NE / 128, NB * NS / 128), 256, 0, stream>>>(
        obufb, Wob, bout, out, nullptr, NB * NS, NE, NE);
}

// Round 8
// 258.728 us; speedup vs baseline: 1.1132x; 1.1132x over previous
//
#include <hip/hip_runtime.h>

#define NB 4
#define NS 2048
#define NE 1024
#define NH 16
#define ND 64
#define KVB 64

typedef unsigned short ushort_t;
typedef __attribute__((ext_vector_type(8))) short bf16x8;
typedef __attribute__((ext_vector_type(4))) float f32x4;

#define SCALE_LOG2E 0.18033688011112042f   // 0.125 * log2(e)

static __device__ __forceinline__ ushort_t f2bf(float f) {
    union { float f; unsigned int u; } v; v.f = f;
    unsigned int r = v.u + 0x7FFF + ((v.u >> 16) & 1);   // RNE
    return (ushort_t)(r >> 16);
}

static __device__ __forceinline__ unsigned pk_bf16(float lo, float hi) {
    unsigned r;
    asm("v_cvt_pk_bf16_f32 %0, %1, %2" : "=v"(r) : "v"(lo), "v"(hi));
    return r;
}

static __device__ __forceinline__ void gload16(const void* g, void* l) {
    __builtin_amdgcn_global_load_lds(
        (const __attribute__((address_space(1))) void*)g,
        (__attribute__((address_space(3))) void*)l,
        16, 0, 0);
}

// ===========================================================================
// fp32 -> bf16 bulk convert  (verified)
// ===========================================================================
__global__ __launch_bounds__(256)
void cvt_f32_bf16(const float* __restrict__ src, ushort_t* __restrict__ dst, int n8)
{
    const int i = blockIdx.x * 256 + threadIdx.x;
    if (i >= n8) return;
    const float4 a = ((const float4*)src)[i * 2];
    const float4 b = ((const float4*)src)[i * 2 + 1];
    union { ushort_t us[8]; uint4 v; } pk;
    pk.us[0] = f2bf(a.x); pk.us[1] = f2bf(a.y); pk.us[2] = f2bf(a.z); pk.us[3] = f2bf(a.w);
    pk.us[4] = f2bf(b.x); pk.us[5] = f2bf(b.y); pk.us[6] = f2bf(b.z); pk.us[7] = f2bf(b.w);
    ((uint4*)dst)[i] = pk.v;
}

// ===========================================================================
// bf16 MFMA GEMM (m97 structure) — verified rounds 2-7, unchanged
// ===========================================================================
template<int EPI>
__global__ __launch_bounds__(256)
void gemm_bf16(const ushort_t* __restrict__ A, const ushort_t* __restrict__ W,
               const float* __restrict__ bias, float* __restrict__ C,
               ushort_t* __restrict__ Cb, int M, int N, int K)
{
    __shared__ ushort_t As[128 * 32];
    __shared__ ushort_t Bs[128 * 32];
    const int tid  = threadIdx.x;
    const int lane = tid & 63;
    const int wid  = tid >> 6;
    const int lr   = lane & 15;
    const int lg   = lane >> 4;
    const int m0 = blockIdx.y * 128;
    const int n0 = blockIdx.x * 128;
    const int wr = wid >> 1, wc = wid & 1;

    size_t srcoff[2];
    int ldsoff[2];
#pragma unroll
    for (int p = 0; p < 2; ++p) {
        const int chunk = p * 256 + tid;
        const int row = chunk >> 2;
        const int sp  = chunk & 3;
        const int c   = sp ^ ((row >> 1) & 3);
        srcoff[p] = (size_t)row * K + c * 8;
        ldsoff[p] = (p * 256 + wid * 64) * 8;
    }
    const ushort_t* Ag = A + (size_t)m0 * K;
    const ushort_t* Wg = W + (size_t)n0 * K;

    int offa[4], offb[4];
#pragma unroll
    for (int f = 0; f < 4; ++f) {
        const int ra = wr * 64 + f * 16 + lr;
        offa[f] = ra * 32 + (lg ^ ((ra >> 1) & 3)) * 8;
        const int rb = wc * 64 + f * 16 + lr;
        offb[f] = rb * 32 + (lg ^ ((rb >> 1) & 3)) * 8;
    }

    f32x4 acc[4][4];
#pragma unroll
    for (int i = 0; i < 4; ++i)
#pragma unroll
        for (int j = 0; j < 4; ++j) acc[i][j] = (f32x4){0.f, 0.f, 0.f, 0.f};

    for (int k0 = 0; k0 < K; k0 += 32) {
        __syncthreads();
#pragma unroll
        for (int p = 0; p < 2; ++p) {
            gload16(Ag + srcoff[p] + k0, (ushort_t*)As + ldsoff[p]);
            gload16(Wg + srcoff[p] + k0, (ushort_t*)Bs + ldsoff[p]);
        }
        __syncthreads();
        bf16x8 af[4], bfr[4];
#pragma unroll
        for (int f = 0; f < 4; ++f) {
            af[f]  = *(const bf16x8*)&As[offa[f]];
            bfr[f] = *(const bf16x8*)&Bs[offb[f]];
        }
#pragma unroll
        for (int mf = 0; mf < 4; ++mf)
#pragma unroll
            for (int nf = 0; nf < 4; ++nf)
                acc[mf][nf] = __builtin_amdgcn_mfma_f32_16x16x32_bf16(
                    af[mf], bfr[nf], acc[mf][nf], 0, 0, 0);
    }

    if (EPI == 0) {
#pragma unroll
        for (int nf = 0; nf < 4; ++nf) {
            const int n = n0 + wc * 64 + nf * 16 + lr;
            const float bj = bias[n];
#pragma unroll
            for (int mf = 0; mf < 4; ++mf)
#pragma unroll
                for (int r = 0; r < 4; ++r) {
                    const int m = m0 + wr * 64 + mf * 16 + lg * 4 + r;
                    C[(size_t)m * N + n] = acc[mf][nf][r] + bj;
                }
        }
    } else {
#pragma unroll
        for (int nf = 0; nf < 4; ++nf) {
            const int n = n0 + wc * 64 + nf * 16 + lr;
            const float bj = bias[n];
            const int t = n >> 10;
            const int h = (n >> 6) & (NH - 1);
            const int d = n & (ND - 1);
#pragma unroll
            for (int mf = 0; mf < 4; ++mf)
#pragma unroll
                for (int r = 0; r < 4; ++r) {
                    const int m = m0 + wr * 64 + mf * 16 + lg * 4 + r;
                    const int b = m >> 11;
                    const int s = m & (NS - 1);
                    Cb[((size_t)((t * NB + b) * NH + h) * NS + s) * ND + d] =
                        f2bf(acc[mf][nf][r] + bj);
                }
        }
    }
}

// ===========================================================================
// RoPE in place on bf16 q,k — verified, unchanged
// ===========================================================================
__global__ __launch_bounds__(256)
void rope_bf16(ushort_t* __restrict__ qkvb, const float* __restrict__ cosT,
               const float* __restrict__ sinT)
{
    const int idx = blockIdx.x * 256 + threadIdx.x;
    const int d0 = (idx & 3) * 8;
    const int s  = (idx >> 2) & (NS - 1);
    const int h  = (idx >> 13) & (NH - 1);
    const int b  = (idx >> 17) & (NB - 1);
    const int t  = idx >> 19;
    ushort_t* base = qkvb + ((size_t)((t * NB + b) * NH + h) * NS + s) * ND;

    union { ushort_t us[8]; uint4 v; } lo, hi, loo, hio;
    lo.v = *(const uint4*)(base + d0);
    hi.v = *(const uint4*)(base + d0 + 32);
    const float4 c0 = *(const float4*)(cosT + s * ND + d0);
    const float4 c1 = *(const float4*)(cosT + s * ND + d0 + 4);
    const float4 s0 = *(const float4*)(sinT + s * ND + d0);
    const float4 s1 = *(const float4*)(sinT + s * ND + d0 + 4);
    const float cc[8] = {c0.x, c0.y, c0.z, c0.w, c1.x, c1.y, c1.z, c1.w};
    const float ss[8] = {s0.x, s0.y, s0.z, s0.w, s1.x, s1.y, s1.z, s1.w};
#pragma unroll
    for (int j = 0; j < 8; ++j) {
        union { unsigned u; float f; } a, bb;
        a.u  = ((unsigned)lo.us[j]) << 16;
        bb.u = ((unsigned)hi.us[j]) << 16;
        loo.us[j] = f2bf(a.f * cc[j] - bb.f * ss[j]);
        hio.us[j] = f2bf(bb.f * cc[j] + a.f * ss[j]);
    }
    *(uint4*)(base + d0)      = loo.v;
    *(uint4*)(base + d0 + 32) = hio.v;
}

// ===========================================================================
// Swapped-operand bf16 MFMA flash attention — r5 structure verbatim
// (2 strips/wave, 128-q block, 3 barriers, T14 prefetch), plus:
//  * XCD-chunked block swizzle: 1D grid 1024; XCD x serves bh in [8x,8x+8)
//    so each XCD's K/V working set (4 MB) is L2-resident  [T1]
//  * s_setprio(1) around MFMA clusters                     [T5]
//  * exp(s*0.125) computed as v_exp_f32(s*0.125*log2e)     [1 less VALU mul]
// ===========================================================================
__global__ __launch_bounds__(256)
void attn_kernel(const ushort_t* __restrict__ qkvb, ushort_t* __restrict__ obuf)
{
    __shared__ ushort_t Ks[64 * 72];
    __shared__ ushort_t Vs[64 * 64];
    __shared__ ushort_t Ps[128 * 72];

    const int tid  = threadIdx.x;
    const int lane = tid & 63;
    const int wid  = tid >> 6;
    const int lr   = lane & 15;
    const int lg   = lane >> 4;

    // bijective digit-swap: consecutive HW block ids (round-robined over the
    // 8 XCDs) map to wg ids whose bh values are chunked 8-per-XCD.
    const int orig = blockIdx.x;                 // 0..1023
    const int wg   = (orig & 7) * 128 + (orig >> 3);
    const int bh   = wg >> 4;
    const int b = bh >> 4, h = bh & (NH - 1);
    const int q0 = (wg & 15) * 128;

    const ushort_t* qbase = qkvb + ((size_t)((0 * NB + b) * NH + h)) * (NS * ND);
    const ushort_t* kbase = qkvb + ((size_t)((1 * NB + b) * NH + h)) * (NS * ND);
    const ushort_t* vbase = qkvb + ((size_t)((2 * NB + b) * NH + h)) * (NS * ND);

    // Q fragments in registers (B operand): qf[strip][k-half]
    bf16x8 qf[2][2];
#pragma unroll
    for (int st = 0; st < 2; ++st)
#pragma unroll
        for (int kh = 0; kh < 2; ++kh)
            qf[st][kh] = *(const bf16x8*)(qbase + (size_t)(q0 + wid * 32 + st * 16 + lr) * ND
                                          + kh * 32 + lg * 8);

    // staging indices: thread covers rows {tid>>3, 32+(tid>>3)}, chunk tid&7
    const int sc = tid & 7;
    const int sr0 = tid >> 3;

    uint4 krg[2], vrg[2];
#pragma unroll
    for (int it = 0; it < 2; ++it) {
        const int r = sr0 + it * 32;
        krg[it] = *(const uint4*)(kbase + r * ND + sc * 8);
        vrg[it] = *(const uint4*)(vbase + r * ND + sc * 8);
    }

    f32x4 acc_o[2][4];
    float lsum[2] = {0.f, 0.f};
#pragma unroll
    for (int st = 0; st < 2; ++st)
#pragma unroll
        for (int dk = 0; dk < 4; ++dk) acc_o[st][dk] = (f32x4){0.f, 0.f, 0.f, 0.f};

    for (int kt = 0; kt < NS; kt += KVB) {
        __syncthreads();                         // B1: prev tile reads done
        // ---- stage K (row-major pad 72) and V (d-major, XOR swizzle) ----
#pragma unroll
        for (int it = 0; it < 2; ++it) {
            const int r = sr0 + it * 32;
            *(uint4*)&Ks[r * 72 + sc * 8] = krg[it];
            union { uint4 v; ushort_t us[8]; } pu;
            pu.v = vrg[it];
#pragma unroll
            for (int j = 0; j < 8; ++j) {
                const int sw = (j ^ sc) << 4;
                Vs[(sc * 8 + j) * 64 + ((((r * 2) ^ sw)) >> 1)] = pu.us[j];
            }
        }
        __syncthreads();                         // B2: staging visible
        // ---- T14: issue next tile's global loads (hide under compute) ----
        if (kt + KVB < NS) {
#pragma unroll
            for (int it = 0; it < 2; ++it) {
                const int r = kt + KVB + sr0 + it * 32;
                krg[it] = *(const uint4*)(kbase + (size_t)r * ND + sc * 8);
                vrg[it] = *(const uint4*)(vbase + (size_t)r * ND + sc * 8);
            }
        }

        // ---- S^T = K Q^T ----
        f32x4 s[2][4];
#pragma unroll
        for (int st = 0; st < 2; ++st)
#pragma unroll
            for (int kvf = 0; kvf < 4; ++kvf) s[st][kvf] = (f32x4){0.f, 0.f, 0.f, 0.f};
        __builtin_amdgcn_s_setprio(1);
#pragma unroll
        for (int kh = 0; kh < 2; ++kh)
#pragma unroll
            for (int kvf = 0; kvf < 4; ++kvf) {
                const bf16x8 kf = *(const bf16x8*)&Ks[(kvf * 16 + lr) * 72 + kh * 32 + lg * 8];
                s[0][kvf] = __builtin_amdgcn_mfma_f32_16x16x32_bf16(kf, qf[0][kh], s[0][kvf], 0, 0, 0);
                s[1][kvf] = __builtin_amdgcn_mfma_f32_16x16x32_bf16(kf, qf[1][kh], s[1][kvf], 0, 0, 0);
            }
        __builtin_amdgcn_s_setprio(0);

        // ---- softmax (no max) + packed P store into q-major Ps ----
#pragma unroll
        for (int st = 0; st < 2; ++st) {
            const int prow = (wid * 32 + st * 16 + lr) * 72;
#pragma unroll
            for (int kvf = 0; kvf < 4; ++kvf) {
                const float p0 = __builtin_amdgcn_exp2f(s[st][kvf][0] * SCALE_LOG2E);
                const float p1 = __builtin_amdgcn_exp2f(s[st][kvf][1] * SCALE_LOG2E);
                const float p2 = __builtin_amdgcn_exp2f(s[st][kvf][2] * SCALE_LOG2E);
                const float p3 = __builtin_amdgcn_exp2f(s[st][kvf][3] * SCALE_LOG2E);
                lsum[st] += (p0 + p1) + (p2 + p3);
                const unsigned w01 = pk_bf16(p0, p1);
                const unsigned w23 = pk_bf16(p2, p3);
                *(uint2*)&Ps[prow + kvf * 16 + lg * 4] = make_uint2(w01, w23);
            }
        }
        __syncthreads();                         // B3: P visible

        // ---- O += P V  (A = P rows, B = V d-major b128) ----
        __builtin_amdgcn_s_setprio(1);
#pragma unroll
        for (int kh = 0; kh < 2; ++kh) {
            const bf16x8 pf0 = *(const bf16x8*)&Ps[(wid * 32 + 0  + lr) * 72 + kh * 32 + lg * 8];
            const bf16x8 pf1 = *(const bf16x8*)&Ps[(wid * 32 + 16 + lr) * 72 + kh * 32 + lg * 8];
#pragma unroll
            for (int dk = 0; dk < 4; ++dk) {
                const int d = dk * 16 + lr;
                const int sw = ((d & 7) ^ ((d >> 3) & 7)) << 4;
                const bf16x8 vf = *(const bf16x8*)&Vs[d * 64 + (((kh * 64 + lg * 16) ^ sw) >> 1)];
                acc_o[0][dk] = __builtin_amdgcn_mfma_f32_16x16x32_bf16(pf0, vf, acc_o[0][dk], 0, 0, 0);
                acc_o[1][dk] = __builtin_amdgcn_mfma_f32_16x16x32_bf16(pf1, vf, acc_o[1][dk], 0, 0, 0);
            }
        }
        __builtin_amdgcn_s_setprio(0);
    }

    // ---- epilogue: row-sum reduce, redistribute, write bf16 O ----
#pragma unroll
    for (int st = 0; st < 2; ++st) {
        float r = lsum[st];
        r += __shfl_xor(r, 16);
        r += __shfl_xor(r, 32);
        float invq[4];
#pragma unroll
        for (int reg = 0; reg < 4; ++reg)
            invq[reg] = 1.0f / __shfl(r, lg * 4 + reg);
#pragma unroll
        for (int dk = 0; dk < 4; ++dk)
#pragma unroll
            for (int reg = 0; reg < 4; ++reg) {
                const int q = q0 + wid * 32 + st * 16 + lg * 4 + reg;
                const int d = dk * 16 + lr;
                obuf[((size_t)(b * NS + q)) * NE + h * ND + d] =
                    f2bf(acc_o[st][dk][reg] * invq[reg]);
            }
    }
}

// ===========================================================================
extern "C" void kernel_launch(void* const* d_in, const int* in_sizes, int n_in,
                              void* d_out, int out_size, void* d_ws, size_t ws_size,
                              hipStream_t stream)
{
    const float* x    = (const float*)d_in[0];
    const float* Win  = (const float*)d_in[1];
    const float* bin  = (const float*)d_in[2];
    const float* Wout = (const float*)d_in[3];
    const float* bout = (const float*)d_in[4];
    const float* cosT = (const float*)d_in[5];
    const float* sinT = (const float*)d_in[6];
    float* out  = (float*)d_out;

    ushort_t* qkvb  = (ushort_t*)d_ws;
    ushort_t* obufb = qkvb + (size_t)3 * NB * NH * NS * ND;
    ushort_t* xb    = obufb + (size_t)NB * NS * NE;
    ushort_t* Wib   = xb + (size_t)NB * NS * NE;
    ushort_t* Wob   = Wib + (size_t)3 * NE * NE;

    const int nx = NB * NS * NE;
    const int nwi = 3 * NE * NE;
    const int nwo = NE * NE;

    cvt_f32_bf16<<<nx / 2048, 256, 0, stream>>>(x, xb, nx / 8);
    cvt_f32_bf16<<<nwi / 2048, 256, 0, stream>>>(Win, Wib, nwi / 8);
    cvt_f32_bf16<<<nwo / 2048, 256, 0, stream>>>(Wout, Wob, nwo / 8);

    gemm_bf16<1><<<dim3(3 * NE / 128, NB * NS / 128), 256, 0, stream>>>(
        xb, Wib, bin, nullptr, qkvb, NB * NS, 3 * NE, NE);
    rope_bf16<<<(2 * NB * NH * NS * 4) / 256, 256, 0, stream>>>(qkvb, cosT, sinT);
    attn_kernel<<<dim3(NB * NH * (NS / 128)), 256, 0, stream>>>(qkvb, obufb);
    gemm_bf16<0><<<dim3(NE / 128, NB * NS / 128), 256, 0, stream>>>(
        obufb, Wob, bout, out, nullptr, NB * NS, NE, NE);
}